// Round 6
// baseline (1793.268 us; speedup 1.0000x reference)
//
#include <hip/hip_runtime.h>
#include <cstdint>
#include <cstddef>

// Problem constants (match reference)
#define NN 100000   // nodes
#define NE 1600000  // edges
#define IN_F 256    // input feats
#define HD 64       // hidden width
#define NC 16       // classes

// Bucketed-build constants
#define NT 391      // dst tiles of 256 nodes: bucket = dst >> 8
#define NBLK 196    // count/fill blocks
#define EPB 8192    // edges per count/fill block (NBLK*EPB >= NE)
#define CM (NT * NBLK)      // counts elems = 76,636
#define SCB 75      // scan blocks: ceil(CM/1024)

// ---------------------------------------------------------------------------
// Workspace layout (bytes):
//   dinv   @ 0           NN floats                               400,000
//   A      @ 400,128     NN*64 floats (h0 -> h2 -> h3)        25,600,000
//   B      @ 26,000,128  NN*64 floats (agg1 -> agg2)          25,600,000
//   counts @ 51,600,128  CM ints (raw -> scanned in place)       306,544
//   bsum   @ 51,906,688  SCB ints
//   bpref  @ 51,907,072  SCB ints
//   [FULL] pairs @ 51,907,456  NE int2 (dst_local<<17|src, ew) 12,800,000
//                              -> end 64,707,456
// Configs (by ws_size, constant per run -> graph-safe):
//   FULL (ws >= 64,800,912): packed payload in ws.
//   DOUT (ws >= 52,000,912): bucketed edge-ids in d_out (NE*4 == out bytes).
//   FALLBACK (else): atomic-scatter path.
// ---------------------------------------------------------------------------

// ---------------- bucket build (no global atomics) -------------------------

__global__ __launch_bounds__(256) void k_count(const int* __restrict__ dstA,
                                               int* __restrict__ counts) {
    __shared__ int hist[NT];
    int tid = threadIdx.x;
    for (int t = tid; t < NT; t += 256) hist[t] = 0;
    __syncthreads();
    int base = blockIdx.x * EPB;
#pragma unroll
    for (int i = 0; i < 32; ++i) {
        int e = base + i * 256 + tid;
        if (e < NE) atomicAdd(&hist[dstA[e] >> 8], 1);  // LDS atomic
    }
    __syncthreads();
    for (int t = tid; t < NT; t += 256)
        counts[t * NBLK + blockIdx.x] = hist[t];
}

// exclusive scan of counts[CM] in place (1024 elems/block; blocks independent)
__global__ __launch_bounds__(256) void k_scan1(int* __restrict__ c,
                                               int* __restrict__ bsum) {
    __shared__ int ss[256];
    int t = threadIdx.x;
    int base = blockIdx.x * 1024 + t * 4;
    int c0 = (base + 0 < CM) ? c[base + 0] : 0;
    int c1 = (base + 1 < CM) ? c[base + 1] : 0;
    int c2 = (base + 2 < CM) ? c[base + 2] : 0;
    int c3 = (base + 3 < CM) ? c[base + 3] : 0;
    int tsum = c0 + c1 + c2 + c3;
    ss[t] = tsum;
    __syncthreads();
    for (int off = 1; off < 256; off <<= 1) {
        int v = (t >= off) ? ss[t - off] : 0;
        __syncthreads();
        ss[t] += v;
        __syncthreads();
    }
    int excl = ss[t] - tsum;
    if (t == 255) bsum[blockIdx.x] = ss[255];
    if (base + 0 < CM) c[base + 0] = excl;
    if (base + 1 < CM) c[base + 1] = excl + c0;
    if (base + 2 < CM) c[base + 2] = excl + c0 + c1;
    if (base + 3 < CM) c[base + 3] = excl + c0 + c1 + c2;
}

__global__ __launch_bounds__(128) void k_scan2(const int* __restrict__ bsum,
                                               int* __restrict__ bpref) {
    __shared__ int ss[128];
    int t = threadIdx.x;
    int v = (t < SCB) ? bsum[t] : 0;
    ss[t] = v;
    __syncthreads();
    for (int off = 1; off < 128; off <<= 1) {
        int u = (t >= off) ? ss[t - off] : 0;
        __syncthreads();
        ss[t] += u;
        __syncthreads();
    }
    if (t < SCB) bpref[t] = ss[t] - v;
}

__global__ __launch_bounds__(256) void k_scan3(int* __restrict__ c,
                                               const int* __restrict__ bpref) {
    int i = blockIdx.x * 256 + threadIdx.x;
    if (i < CM) c[i] += bpref[i >> 10];
}

// fill bucket segments. counts is READ-ONLY here (bases copied to LDS),
// so the scanned prefix survives for dinvb/aggb bucket-range lookups.
template <bool FULL>
__global__ __launch_bounds__(256) void k_fill(const int* __restrict__ srcA,
                                              const int* __restrict__ dstA,
                                              const float* __restrict__ ew,
                                              const int* __restrict__ counts,
                                              int2* __restrict__ pairs,
                                              int* __restrict__ eid) {
    __shared__ int basel[NT];
    int tid = threadIdx.x;
    for (int t = tid; t < NT; t += 256) basel[t] = counts[t * NBLK + blockIdx.x];
    __syncthreads();
    int eb = blockIdx.x * EPB;
#pragma unroll
    for (int i = 0; i < 32; ++i) {
        int e = eb + i * 256 + tid;
        if (e < NE) {
            int d = dstA[e];
            int pos = atomicAdd(&basel[d >> 8], 1);  // LDS atomic
            if (FULL) {
                int pk = srcA[e] | ((d & 255) << 17);  // src<2^17, dl<2^8
                pairs[pos] = make_int2(pk, __float_as_int(ew[e]));
            } else {
                eid[pos] = e;
            }
        }
    }
}

// per-tile degree via LDS accumulation -> dinv = rsqrt(1 + sum ew)
template <bool FULL>
__global__ __launch_bounds__(256) void k_dinvb(const int* __restrict__ counts,
                                               const int2* __restrict__ pairs,
                                               const int* __restrict__ eid,
                                               const int* __restrict__ dstA,
                                               const float* __restrict__ ew,
                                               float* __restrict__ dinv) {
    __shared__ float degl[256];
    int tid = threadIdx.x;
    int tile = blockIdx.x;
    degl[tid] = 0.0f;
    __syncthreads();
    int bs = counts[tile * NBLK];
    int be = (tile + 1 < NT) ? counts[(tile + 1) * NBLK] : NE;
    for (int p = bs + tid; p < be; p += 256) {
        if (FULL) {
            int2 v = pairs[p];
            atomicAdd(&degl[(v.x >> 17) & 255], __int_as_float(v.y));
        } else {
            int e = eid[p];
            atomicAdd(&degl[dstA[e] & 255], ew[e]);
        }
    }
    __syncthreads();
    int row = tile * 256 + tid;
    if (row < NN) dinv[row] = rsqrtf(1.0f + degl[tid]);
}

// aggregate: one block per 256-row tile, 64KB LDS accumulator.
// acc init = self-loop h[row]*dinv^2; wave-per-edge gather + ds_add_f32.
template <bool FULL>
__global__ __launch_bounds__(1024) void k_aggb(const int* __restrict__ counts,
                                               const int2* __restrict__ pairs,
                                               const int* __restrict__ eid,
                                               const int* __restrict__ srcA,
                                               const int* __restrict__ dstA,
                                               const float* __restrict__ ew,
                                               const float* __restrict__ dinv,
                                               const float* __restrict__ h,
                                               float* __restrict__ agg) {
    __shared__ float acc[256 * HD];  // 64 KB
    int tid = threadIdx.x;
    int tile = blockIdx.x;
    int rb = tile * 256;
    for (int i = tid; i < 256 * HD; i += 1024) {
        int row = rb + (i >> 6);
        float v = 0.0f;
        if (row < NN) {
            float di = dinv[row];
            v = h[(size_t)row * HD + (i & 63)] * di * di;
        }
        acc[i] = v;
    }
    __syncthreads();
    int bs = counts[tile * NBLK];
    int be = (tile + 1 < NT) ? counts[(tile + 1) * NBLK] : NE;
    int len = be - bs;
    int w = tid >> 6, lane = tid & 63;
    int chunk = (len + 15) >> 4;
    int p  = bs + w * chunk;
    int pe = min(p + chunk, be);
    if (FULL) {
        for (; p + 4 <= pe; p += 4) {
            int2 v0 = pairs[p], v1 = pairs[p + 1], v2 = pairs[p + 2], v3 = pairs[p + 3];
            int s0 = v0.x & 0x1FFFF, s1 = v1.x & 0x1FFFF,
                s2 = v2.x & 0x1FFFF, s3 = v3.x & 0x1FFFF;
            int d0 = v0.x >> 17, d1 = v1.x >> 17, d2 = v2.x >> 17, d3 = v3.x >> 17;
            float h0 = h[(size_t)s0 * HD + lane];
            float h1 = h[(size_t)s1 * HD + lane];
            float h2 = h[(size_t)s2 * HD + lane];
            float h3 = h[(size_t)s3 * HD + lane];
            float n0 = dinv[s0] * __int_as_float(v0.y) * dinv[rb + d0];
            float n1 = dinv[s1] * __int_as_float(v1.y) * dinv[rb + d1];
            float n2 = dinv[s2] * __int_as_float(v2.y) * dinv[rb + d2];
            float n3 = dinv[s3] * __int_as_float(v3.y) * dinv[rb + d3];
            atomicAdd(&acc[d0 * HD + lane], n0 * h0);
            atomicAdd(&acc[d1 * HD + lane], n1 * h1);
            atomicAdd(&acc[d2 * HD + lane], n2 * h2);
            atomicAdd(&acc[d3 * HD + lane], n3 * h3);
        }
        for (; p < pe; ++p) {
            int2 v = pairs[p];
            int s = v.x & 0x1FFFF, dl = v.x >> 17;
            float nrm = dinv[s] * __int_as_float(v.y) * dinv[rb + dl];
            atomicAdd(&acc[dl * HD + lane], nrm * h[(size_t)s * HD + lane]);
        }
    } else {
        for (; p + 4 <= pe; p += 4) {
            int e0 = eid[p], e1 = eid[p + 1], e2 = eid[p + 2], e3 = eid[p + 3];
            int s0 = srcA[e0], s1 = srcA[e1], s2 = srcA[e2], s3 = srcA[e3];
            int d0 = dstA[e0] & 255, d1 = dstA[e1] & 255,
                d2 = dstA[e2] & 255, d3 = dstA[e3] & 255;
            float h0 = h[(size_t)s0 * HD + lane];
            float h1 = h[(size_t)s1 * HD + lane];
            float h2 = h[(size_t)s2 * HD + lane];
            float h3 = h[(size_t)s3 * HD + lane];
            float n0 = dinv[s0] * ew[e0] * dinv[rb + d0];
            float n1 = dinv[s1] * ew[e1] * dinv[rb + d1];
            float n2 = dinv[s2] * ew[e2] * dinv[rb + d2];
            float n3 = dinv[s3] * ew[e3] * dinv[rb + d3];
            atomicAdd(&acc[d0 * HD + lane], n0 * h0);
            atomicAdd(&acc[d1 * HD + lane], n1 * h1);
            atomicAdd(&acc[d2 * HD + lane], n2 * h2);
            atomicAdd(&acc[d3 * HD + lane], n3 * h3);
        }
        for (; p < pe; ++p) {
            int e = eid[p];
            int s = srcA[e], dl = dstA[e] & 255;
            float nrm = dinv[s] * ew[e] * dinv[rb + dl];
            atomicAdd(&acc[dl * HD + lane], nrm * h[(size_t)s * HD + lane]);
        }
    }
    __syncthreads();
    for (int i = tid; i < 256 * HD; i += 1024) {
        int row = rb + (i >> 6);
        if (row < NN) agg[(size_t)row * HD + (i & 63)] = acc[i];
    }
}

// ---------------------------------------------------------------------------
// GEMMs + output (unchanged structure)
// ---------------------------------------------------------------------------
#define FMA16(xv)                                                      \
    acc[0] = fmaf(xv, w0.x, acc[0]);  acc[1] = fmaf(xv, w0.y, acc[1]); \
    acc[2] = fmaf(xv, w0.z, acc[2]);  acc[3] = fmaf(xv, w0.w, acc[3]); \
    acc[4] = fmaf(xv, w1.x, acc[4]);  acc[5] = fmaf(xv, w1.y, acc[5]); \
    acc[6] = fmaf(xv, w1.z, acc[6]);  acc[7] = fmaf(xv, w1.w, acc[7]); \
    acc[8] = fmaf(xv, w2.x, acc[8]);  acc[9] = fmaf(xv, w2.y, acc[9]); \
    acc[10] = fmaf(xv, w2.z, acc[10]); acc[11] = fmaf(xv, w2.w, acc[11]); \
    acc[12] = fmaf(xv, w3.x, acc[12]); acc[13] = fmaf(xv, w3.y, acc[13]); \
    acc[14] = fmaf(xv, w3.z, acc[14]); acc[15] = fmaf(xv, w3.w, acc[15]);

__global__ __launch_bounds__(256, 4) void k_gemm1(const float* __restrict__ x,
                                                  const float* __restrict__ W1,
                                                  float* __restrict__ h0) {
    __shared__ float sW[64 * HD];
    int tid = threadIdx.x;
    int rt  = tid >> 2;
    int cg  = (tid & 3) * 16;
    int base = blockIdx.x * 256;
    int rowc[4];
    bool rv[4];
#pragma unroll
    for (int r = 0; r < 4; ++r) {
        int row = base + rt + 64 * r;
        rv[r] = row < NN;
        rowc[r] = rv[r] ? row : (NN - 1);
    }
    float acc[4][16];
#pragma unroll
    for (int r = 0; r < 4; ++r)
#pragma unroll
        for (int c = 0; c < 16; ++c) acc[r][c] = 0.0f;

    for (int kc = 0; kc < IN_F; kc += 64) {
        __syncthreads();
        {
            const float4* wsrc = (const float4*)(W1 + (size_t)kc * HD);
            float4* wdst = (float4*)sW;
#pragma unroll
            for (int q = 0; q < 4; ++q) wdst[q * 256 + tid] = wsrc[q * 256 + tid];
        }
        __syncthreads();
        for (int k4 = 0; k4 < 16; ++k4) {
            float xs[4][4];
#pragma unroll
            for (int r = 0; r < 4; ++r)
                *(float4*)xs[r] = *(const float4*)(x + (size_t)rowc[r] * IN_F + kc + k4 * 4);
#pragma unroll
            for (int j = 0; j < 4; ++j) {
                float wv[16];
                const float4* wr4 = (const float4*)(sW + (k4 * 4 + j) * HD + cg);
#pragma unroll
                for (int q = 0; q < 4; ++q) ((float4*)wv)[q] = wr4[q];
#pragma unroll
                for (int r = 0; r < 4; ++r) {
                    float xj = xs[r][j];
#pragma unroll
                    for (int c = 0; c < 16; ++c) acc[r][c] = fmaf(xj, wv[c], acc[r][c]);
                }
            }
        }
    }
#pragma unroll
    for (int r = 0; r < 4; ++r) {
        if (!rv[r]) continue;
        float4* hp = (float4*)(h0 + (size_t)rowc[r] * HD + cg);
#pragma unroll
        for (int q = 0; q < 4; ++q)
            hp[q] = make_float4(acc[r][q * 4], acc[r][q * 4 + 1],
                                acc[r][q * 4 + 2], acc[r][q * 4 + 3]);
    }
}

template <bool BIASRELU>
__global__ __launch_bounds__(256, 4) void k_gemm64(const float* __restrict__ in,
                                                   const float* __restrict__ bin,
                                                   const float* __restrict__ W,
                                                   const float* __restrict__ bout,
                                                   float* __restrict__ outA) {
    __shared__ float sW[HD * HD];
    __shared__ float sBin[HD];
    int tid = threadIdx.x;
    int rt  = tid >> 2;
    int cg  = (tid & 3) * 16;
    int base = blockIdx.x * 256;
    int rowc[4];
    bool rv[4];
#pragma unroll
    for (int r = 0; r < 4; ++r) {
        int row = base + rt + 64 * r;
        rv[r] = row < NN;
        rowc[r] = rv[r] ? row : (NN - 1);
    }
    {
        const float4* wsrc = (const float4*)W;
        float4* wdst = (float4*)sW;
#pragma unroll
        for (int q = 0; q < 4; ++q) wdst[q * 256 + tid] = wsrc[q * 256 + tid];
        if (tid < 16) ((float4*)sBin)[tid] = ((const float4*)bin)[tid];
    }
    __syncthreads();
    float acc[4][16];
#pragma unroll
    for (int r = 0; r < 4; ++r)
#pragma unroll
        for (int c = 0; c < 16; ++c) acc[r][c] = 0.0f;

    for (int k4 = 0; k4 < 16; ++k4) {
        float bs[4];
        *(float4*)bs = ((const float4*)sBin)[k4];
        float xs[4][4];
#pragma unroll
        for (int r = 0; r < 4; ++r)
            *(float4*)xs[r] = *(const float4*)(in + (size_t)rowc[r] * HD + k4 * 4);
#pragma unroll
        for (int j = 0; j < 4; ++j) {
            float wv[16];
            const float4* wr4 = (const float4*)(sW + (k4 * 4 + j) * HD + cg);
#pragma unroll
            for (int q = 0; q < 4; ++q) ((float4*)wv)[q] = wr4[q];
#pragma unroll
            for (int r = 0; r < 4; ++r) {
                float hv = fmaxf(xs[r][j] + bs[j], 0.0f);
#pragma unroll
                for (int c = 0; c < 16; ++c) acc[r][c] = fmaf(hv, wv[c], acc[r][c]);
            }
        }
    }
#pragma unroll
    for (int r = 0; r < 4; ++r) {
        if (!rv[r]) continue;
        float4* ha = (float4*)(outA + (size_t)rowc[r] * HD + cg);
        if (BIASRELU) {
            float bo[16];
#pragma unroll
            for (int q = 0; q < 4; ++q) ((float4*)bo)[q] = *(const float4*)(bout + cg + q * 4);
#pragma unroll
            for (int q = 0; q < 4; ++q) {
                float4 v;
                v.x = fmaxf(acc[r][q * 4 + 0] + bo[q * 4 + 0], 0.0f);
                v.y = fmaxf(acc[r][q * 4 + 1] + bo[q * 4 + 1], 0.0f);
                v.z = fmaxf(acc[r][q * 4 + 2] + bo[q * 4 + 2], 0.0f);
                v.w = fmaxf(acc[r][q * 4 + 3] + bo[q * 4 + 3], 0.0f);
                ha[q] = v;
            }
        } else {
#pragma unroll
            for (int q = 0; q < 4; ++q)
                ha[q] = make_float4(acc[r][q * 4], acc[r][q * 4 + 1],
                                    acc[r][q * 4 + 2], acc[r][q * 4 + 3]);
        }
    }
}

// --- fallback path kernels (unchanged) ---
__global__ __launch_bounds__(256) void k_init_fb(float* __restrict__ deg) {
    int i = blockIdx.x * 256 + threadIdx.x;
    if (i < NN) deg[i] = 1.0f;
}

__global__ __launch_bounds__(256) void k_edge_fb(const int* __restrict__ dst,
                                                 const float* __restrict__ ew,
                                                 float* __restrict__ deg) {
    int e = blockIdx.x * 256 + threadIdx.x;
    if (e < NE) atomicAdd(&deg[dst[e]], ew[e]);
}

__global__ __launch_bounds__(256) void k_dinv_fb(float* __restrict__ deg) {
    int i = blockIdx.x * 256 + threadIdx.x;
    if (i < NN) {
        float d = deg[i];
        deg[i] = d > 0.0f ? rsqrtf(d) : 0.0f;
    }
}

__global__ __launch_bounds__(256) void k_selfloop(const float* __restrict__ h,
                                                  const float* __restrict__ dinv,
                                                  float* __restrict__ agg) {
    int i = blockIdx.x * 256 + threadIdx.x;
    if (i >= NN * (HD / 4)) return;
    int row = i / (HD / 4);
    float di = dinv[row];
    float d2 = di * di;
    float4 v = ((const float4*)h)[i];
    ((float4*)agg)[i] = make_float4(v.x * d2, v.y * d2, v.z * d2, v.w * d2);
}

__global__ __launch_bounds__(256) void k_scatter(const int* __restrict__ src,
                                                 const int* __restrict__ dst,
                                                 const float* __restrict__ ew,
                                                 const float* __restrict__ dinv,
                                                 const float* __restrict__ h,
                                                 float* __restrict__ agg) {
    int e = blockIdx.x * 4 + (threadIdx.x >> 6);
    int lane = threadIdx.x & 63;
    if (e >= NE) return;
    int s = src[e];
    int d = dst[e];
    float nrm = dinv[s] * ew[e] * dinv[d];
    float v = h[(size_t)s * HD + lane] * nrm;
    atomicAdd(&agg[(size_t)d * HD + lane], v);
}

// logits = h3 @ Wm2 + bm2, softmax. Wm2 (4 KB) in LDS, 4 rows/thread.
__global__ __launch_bounds__(256, 4) void k_out(const float* __restrict__ h3,
                                                const float* __restrict__ Wm2,
                                                const float* __restrict__ bm2,
                                                float* __restrict__ out) {
    __shared__ float sW[HD * NC];
    int tid = threadIdx.x;
    ((float4*)sW)[tid] = ((const float4*)Wm2)[tid];
    __syncthreads();
    int base = blockIdx.x * 1024;
    int rowc[4];
    bool rv[4];
#pragma unroll
    for (int r = 0; r < 4; ++r) {
        int row = base + tid * 4 + r;
        rv[r] = row < NN;
        rowc[r] = rv[r] ? row : (NN - 1);
    }
    float acc[4][16];
#pragma unroll
    for (int r = 0; r < 4; ++r)
#pragma unroll
        for (int c = 0; c < 16; ++c) acc[r][c] = 0.0f;

    for (int k4 = 0; k4 < 16; ++k4) {
        float xs[4][4];
#pragma unroll
        for (int r = 0; r < 4; ++r)
            *(float4*)xs[r] = *(const float4*)(h3 + (size_t)rowc[r] * HD + k4 * 4);
#pragma unroll
        for (int j = 0; j < 4; ++j) {
            float wv[16];
            const float4* wr4 = (const float4*)(sW + (k4 * 4 + j) * NC);
#pragma unroll
            for (int q = 0; q < 4; ++q) ((float4*)wv)[q] = wr4[q];
#pragma unroll
            for (int r = 0; r < 4; ++r) {
                float xj = xs[r][j];
#pragma unroll
                for (int c = 0; c < 16; ++c) acc[r][c] = fmaf(xj, wv[c], acc[r][c]);
            }
        }
    }
    float bm[16];
#pragma unroll
    for (int q = 0; q < 4; ++q) ((float4*)bm)[q] = ((const float4*)bm2)[q];
#pragma unroll
    for (int r = 0; r < 4; ++r) {
        if (!rv[r]) continue;
        float l[16];
#pragma unroll
        for (int c = 0; c < 16; ++c) l[c] = acc[r][c] + bm[c];
        float m = l[0];
#pragma unroll
        for (int c = 1; c < 16; ++c) m = fmaxf(m, l[c]);
        float ssum = 0.0f;
#pragma unroll
        for (int c = 0; c < 16; ++c) {
            l[c] = expf(l[c] - m);
            ssum += l[c];
        }
        float inv = 1.0f / ssum;
        float4* op = (float4*)(out + (size_t)rowc[r] * NC);
#pragma unroll
        for (int q = 0; q < 4; ++q)
            op[q] = make_float4(l[q * 4] * inv, l[q * 4 + 1] * inv,
                                l[q * 4 + 2] * inv, l[q * 4 + 3] * inv);
    }
}

extern "C" void kernel_launch(void* const* d_in, const int* in_sizes, int n_in,
                              void* d_out, int out_size, void* d_ws, size_t ws_size,
                              hipStream_t stream) {
    const float* x   = (const float*)d_in[0];
    const int*   ei  = (const int*)d_in[1];   // (2, E): [0,E)=src, [E,2E)=dst
    const float* ew  = (const float*)d_in[2];
    const float* W1  = (const float*)d_in[3];
    const float* b1  = (const float*)d_in[4];
    const float* W2  = (const float*)d_in[5];
    const float* b2  = (const float*)d_in[6];
    const float* Wm1 = (const float*)d_in[7];
    const float* bm1 = (const float*)d_in[8];
    const float* Wm2 = (const float*)d_in[9];
    const float* bm2 = (const float*)d_in[10];
    float* out = (float*)d_out;

    char* base = (char*)d_ws;
    float* dinv  = (float*)base;
    float* A     = (float*)(base + 400128);
    float* B     = (float*)(base + 26000128);
    int*   counts = (int*)(base + 51600128);
    int*   bsum   = (int*)(base + 51906688);
    int*   bpref  = (int*)(base + 51907072);
    int2*  pairs  = (int2*)(base + 51907456);

    const int* src = ei;
    const int* dst = ei + NE;

    const bool full  = ws_size >= (size_t)64800912;
    const bool douta = !full && ws_size >= (size_t)52000912;
    const int g_node = (NN + 255) / 256;   // 391
    const int g_gemm = (NN + 255) / 256;   // 391
    int* eid = (int*)d_out;

    if (full || douta) {
        // gemm1: A = x @ W1
        k_gemm1<<<dim3(g_gemm), dim3(256), 0, stream>>>(x, W1, A);
        // bucket build (no global atomics)
        k_count<<<dim3(NBLK), dim3(256), 0, stream>>>(dst, counts);
        k_scan1<<<dim3(SCB), dim3(256), 0, stream>>>(counts, bsum);
        k_scan2<<<dim3(1), dim3(128), 0, stream>>>(bsum, bpref);
        k_scan3<<<dim3((CM + 255) / 256), dim3(256), 0, stream>>>(counts, bpref);
        if (full) {
            k_fill<true><<<dim3(NBLK), dim3(256), 0, stream>>>(src, dst, ew, counts, pairs, nullptr);
            k_dinvb<true><<<dim3(NT), dim3(256), 0, stream>>>(counts, pairs, nullptr, dst, ew, dinv);
            k_aggb<true><<<dim3(NT), dim3(1024), 0, stream>>>(counts, pairs, nullptr, src, dst, ew, dinv, A, B);
            k_gemm64<false><<<dim3(g_gemm), dim3(256), 0, stream>>>(B, b1, W2, nullptr, A);
            k_aggb<true><<<dim3(NT), dim3(1024), 0, stream>>>(counts, pairs, nullptr, src, dst, ew, dinv, A, B);
        } else {
            k_fill<false><<<dim3(NBLK), dim3(256), 0, stream>>>(src, dst, ew, counts, nullptr, eid);
            k_dinvb<false><<<dim3(NT), dim3(256), 0, stream>>>(counts, nullptr, eid, dst, ew, dinv);
            k_aggb<false><<<dim3(NT), dim3(1024), 0, stream>>>(counts, nullptr, eid, src, dst, ew, dinv, A, B);
            k_gemm64<false><<<dim3(g_gemm), dim3(256), 0, stream>>>(B, b1, W2, nullptr, A);
            k_aggb<false><<<dim3(NT), dim3(1024), 0, stream>>>(counts, nullptr, eid, src, dst, ew, dinv, A, B);
        }
        k_gemm64<true><<<dim3(g_gemm), dim3(256), 0, stream>>>(B, b2, Wm1, bm1, A);
        k_out<<<dim3((NN + 1023) / 1024), dim3(256), 0, stream>>>(A, Wm2, bm2, out);
    } else {
        // fallback: atomic scatter
        k_init_fb<<<dim3(g_node), dim3(256), 0, stream>>>(dinv);
        k_edge_fb<<<dim3(NE / 256), dim3(256), 0, stream>>>(dst, ew, dinv);
        k_dinv_fb<<<dim3(g_node), dim3(256), 0, stream>>>(dinv);
        k_gemm1<<<dim3(g_gemm), dim3(256), 0, stream>>>(x, W1, A);
        k_selfloop<<<dim3((NN * (HD / 4) + 255) / 256), dim3(256), 0, stream>>>(A, dinv, B);
        k_scatter<<<dim3(NE / 4), dim3(256), 0, stream>>>(src, dst, ew, dinv, A, B);
        k_gemm64<false><<<dim3(g_gemm), dim3(256), 0, stream>>>(B, b1, W2, nullptr, A);
        k_selfloop<<<dim3((NN * (HD / 4) + 255) / 256), dim3(256), 0, stream>>>(A, dinv, B);
        k_scatter<<<dim3(NE / 4), dim3(256), 0, stream>>>(src, dst, ew, dinv, A, B);
        k_gemm64<true><<<dim3(g_gemm), dim3(256), 0, stream>>>(B, b2, Wm1, bm1, A);
        k_out<<<dim3((NN + 1023) / 1024), dim3(256), 0, stream>>>(A, Wm2, bm2, out);
    }
}

// Round 7
// 572.293 us; speedup vs baseline: 3.1335x; 3.1335x over previous
//
#include <hip/hip_runtime.h>
#include <cstdint>
#include <cstddef>

// Problem constants (match reference)
#define NN 100000   // nodes
#define NE 1600000  // edges
#define IN_F 256    // input feats
#define HD 64       // hidden width
#define NC 16       // classes

// Bucketed-build constants
#define NT 391      // dst tiles of 256 nodes: tile = dst >> 8
#define NBLK 196    // count/fill blocks
#define EPB 8192    // edges per count/fill block (NBLK*EPB >= NE)
#define CM (NT * NBLK)   // counts elems = 76,636
#define SCB 75      // scan blocks: ceil(CM/1024)

// ---------------------------------------------------------------------------
// Workspace layout (bytes) — guaranteed budget 52,000,912 (proven R4-R6):
//   dinv   @ 0             NN floats                              400,000
//   A      @ 400,128       NN*64 floats (h0 -> h2 -> h3)       25,600,000
//          (tmp int2[NE] = 12.8 MB aliases A BEFORE k_gemm1 runs)
//   B      @ 26,000,128    NN*64 floats (agg1 -> agg2)         25,600,000
//          (counts/bsum/bpref alias B's head BEFORE agg1 writes B)
//   rowptr @ 51,600,128    (NN+1) ints                             400,004
//   [FULL only] pairsS @ 52,000,256  NE int2 (src|dl<<17, ew)  12,800,000
//                                    -> end 64,800,256
// Configs (by ws_size, constant per run -> graph-safe):
//   FULL (ws >= 64,800,912): row-sorted (src,ew) pairs in ws; 1-indirection.
//   DOUT (ws >= 52,000,912): row-sorted edge-ids in d_out; 2-indirection.
//   FALLBACK (else): atomic-scatter path.
// No global atomics and no LDS *float* atomics anywhere on the main path.
// ---------------------------------------------------------------------------

// ---------------- tile-bucket build (LDS int atomics only) -----------------

__global__ __launch_bounds__(256) void k_count(const int* __restrict__ dstA,
                                               int* __restrict__ counts) {
    __shared__ int hist[NT];
    int tid = threadIdx.x;
    for (int t = tid; t < NT; t += 256) hist[t] = 0;
    __syncthreads();
    int base = blockIdx.x * EPB;
#pragma unroll
    for (int i = 0; i < 32; ++i) {
        int e = base + i * 256 + tid;
        if (e < NE) atomicAdd(&hist[dstA[e] >> 8], 1);  // native ds_add_u32
    }
    __syncthreads();
    for (int t = tid; t < NT; t += 256)
        counts[t * NBLK + blockIdx.x] = hist[t];
}

// exclusive scan of counts[CM] in place
__global__ __launch_bounds__(256) void k_scan1(int* __restrict__ c,
                                               int* __restrict__ bsum) {
    __shared__ int ss[256];
    int t = threadIdx.x;
    int base = blockIdx.x * 1024 + t * 4;
    int c0 = (base + 0 < CM) ? c[base + 0] : 0;
    int c1 = (base + 1 < CM) ? c[base + 1] : 0;
    int c2 = (base + 2 < CM) ? c[base + 2] : 0;
    int c3 = (base + 3 < CM) ? c[base + 3] : 0;
    int tsum = c0 + c1 + c2 + c3;
    ss[t] = tsum;
    __syncthreads();
    for (int off = 1; off < 256; off <<= 1) {
        int v = (t >= off) ? ss[t - off] : 0;
        __syncthreads();
        ss[t] += v;
        __syncthreads();
    }
    int excl = ss[t] - tsum;
    if (t == 255) bsum[blockIdx.x] = ss[255];
    if (base + 0 < CM) c[base + 0] = excl;
    if (base + 1 < CM) c[base + 1] = excl + c0;
    if (base + 2 < CM) c[base + 2] = excl + c0 + c1;
    if (base + 3 < CM) c[base + 3] = excl + c0 + c1 + c2;
}

__global__ __launch_bounds__(128) void k_scan2(const int* __restrict__ bsum,
                                               int* __restrict__ bpref) {
    __shared__ int ss[128];
    int t = threadIdx.x;
    int v = (t < SCB) ? bsum[t] : 0;
    ss[t] = v;
    __syncthreads();
    for (int off = 1; off < 128; off <<= 1) {
        int u = (t >= off) ? ss[t - off] : 0;
        __syncthreads();
        ss[t] += u;
        __syncthreads();
    }
    if (t < SCB) bpref[t] = ss[t] - v;
}

__global__ __launch_bounds__(256) void k_scan3(int* __restrict__ c,
                                               const int* __restrict__ bpref) {
    int i = blockIdx.x * 256 + threadIdx.x;
    if (i < CM) c[i] += bpref[i >> 10];
}

// fill tile buckets: tmp[pos] = FULL ? (src|dl<<17, ew) : (eid, dl)
template <bool FULL>
__global__ __launch_bounds__(256) void k_fill2(const int* __restrict__ srcA,
                                               const int* __restrict__ dstA,
                                               const float* __restrict__ ew,
                                               const int* __restrict__ counts,
                                               int2* __restrict__ tmp) {
    __shared__ int basel[NT];
    int tid = threadIdx.x;
    for (int t = tid; t < NT; t += 256) basel[t] = counts[t * NBLK + blockIdx.x];
    __syncthreads();
    int eb = blockIdx.x * EPB;
#pragma unroll
    for (int i = 0; i < 32; ++i) {
        int e = eb + i * 256 + tid;
        if (e < NE) {
            int d = dstA[e];
            int pos = atomicAdd(&basel[d >> 8], 1);  // native LDS int atomic
            if (FULL)
                tmp[pos] = make_int2(srcA[e] | ((d & 255) << 17),
                                     __float_as_int(ew[e]));
            else
                tmp[pos] = make_int2(e, d & 255);
        }
    }
}

// per-tile counting sort to row granularity. Writes rowptr + sorted payload.
// FULL: outP[pos] = (src|dl<<17, ew).  DOUT: outE[pos] = eid.
template <bool FULL>
__global__ __launch_bounds__(256) void k_sort(const int* __restrict__ counts,
                                              const int2* __restrict__ tmp,
                                              int2* __restrict__ outP,
                                              int* __restrict__ outE,
                                              int* __restrict__ rowptr) {
    __shared__ int hist[256], ss[256], bases[256];
    int tid = threadIdx.x;
    int tile = blockIdx.x;
    int bs = counts[tile * NBLK];
    int be = (tile + 1 < NT) ? counts[(tile + 1) * NBLK] : NE;
    hist[tid] = 0;
    __syncthreads();
    for (int p = bs + tid; p < be; p += 256) {
        int dl = FULL ? ((tmp[p].x >> 17) & 255) : tmp[p].y;
        atomicAdd(&hist[dl], 1);  // native LDS int atomic
    }
    __syncthreads();
    int v = hist[tid];
    ss[tid] = v;
    __syncthreads();
    for (int off = 1; off < 256; off <<= 1) {
        int u = (tid >= off) ? ss[tid - off] : 0;
        __syncthreads();
        ss[tid] += u;
        __syncthreads();
    }
    int excl = ss[tid] - v;
    bases[tid] = bs + excl;
    int row = tile * 256 + tid;
    if (row < NN) rowptr[row] = bs + excl;
    if (tile == NT - 1 && tid == 0) rowptr[NN] = NE;
    __syncthreads();
    for (int p = bs + tid; p < be; p += 256) {
        int2 t2 = tmp[p];
        int dl = FULL ? ((t2.x >> 17) & 255) : t2.y;
        int pos = atomicAdd(&bases[dl], 1);
        if (FULL) outP[pos] = t2;
        else      outE[pos] = t2.x;
    }
}

// dinv[i] = rsqrt(1 + sum ew over row i) — sequential per thread, no atomics
template <bool FULL>
__global__ __launch_bounds__(256) void k_degdinv(const int* __restrict__ rowptr,
                                                 const int2* __restrict__ pairsS,
                                                 const int* __restrict__ eid,
                                                 const float* __restrict__ ew,
                                                 float* __restrict__ dinv) {
    int i = blockIdx.x * 256 + threadIdx.x;
    if (i >= NN) return;
    int p = rowptr[i], pe = rowptr[i + 1];
    float s = 1.0f;
    for (; p < pe; ++p)
        s += FULL ? __int_as_float(pairsS[p].y) : ew[eid[p]];
    dinv[i] = rsqrtf(s);
}

// aggregate: one wave per dst row, lane = feature, register accumulate.
template <bool FULL>
__global__ __launch_bounds__(256) void k_agg(const int* __restrict__ rowptr,
                                             const int2* __restrict__ pairsS,
                                             const int* __restrict__ eid,
                                             const int* __restrict__ srcA,
                                             const float* __restrict__ ew,
                                             const float* __restrict__ dinv,
                                             const float* __restrict__ h,
                                             float* __restrict__ agg) {
    int row = blockIdx.x * 4 + (threadIdx.x >> 6);
    int lane = threadIdx.x & 63;
    if (row >= NN) return;
    int p = rowptr[row], pe = rowptr[row + 1];
    float di = dinv[row];
    float acc = h[(size_t)row * HD + lane] * di * di;
    if (FULL) {
        for (; p + 4 <= pe; p += 4) {
            int2 v0 = pairsS[p], v1 = pairsS[p + 1],
                 v2 = pairsS[p + 2], v3 = pairsS[p + 3];
            int s0 = v0.x & 0x1FFFF, s1 = v1.x & 0x1FFFF,
                s2 = v2.x & 0x1FFFF, s3 = v3.x & 0x1FFFF;
            float h0 = h[(size_t)s0 * HD + lane];
            float h1 = h[(size_t)s1 * HD + lane];
            float h2 = h[(size_t)s2 * HD + lane];
            float h3 = h[(size_t)s3 * HD + lane];
            float n0 = dinv[s0] * __int_as_float(v0.y) * di;
            float n1 = dinv[s1] * __int_as_float(v1.y) * di;
            float n2 = dinv[s2] * __int_as_float(v2.y) * di;
            float n3 = dinv[s3] * __int_as_float(v3.y) * di;
            acc = fmaf(n0, h0, acc);
            acc = fmaf(n1, h1, acc);
            acc = fmaf(n2, h2, acc);
            acc = fmaf(n3, h3, acc);
        }
        for (; p < pe; ++p) {
            int2 v = pairsS[p];
            int s = v.x & 0x1FFFF;
            acc = fmaf(dinv[s] * __int_as_float(v.y) * di,
                       h[(size_t)s * HD + lane], acc);
        }
    } else {
        for (; p + 4 <= pe; p += 4) {
            int e0 = eid[p], e1 = eid[p + 1], e2 = eid[p + 2], e3 = eid[p + 3];
            int s0 = srcA[e0], s1 = srcA[e1], s2 = srcA[e2], s3 = srcA[e3];
            float h0 = h[(size_t)s0 * HD + lane];
            float h1 = h[(size_t)s1 * HD + lane];
            float h2 = h[(size_t)s2 * HD + lane];
            float h3 = h[(size_t)s3 * HD + lane];
            float n0 = dinv[s0] * ew[e0] * di;
            float n1 = dinv[s1] * ew[e1] * di;
            float n2 = dinv[s2] * ew[e2] * di;
            float n3 = dinv[s3] * ew[e3] * di;
            acc = fmaf(n0, h0, acc);
            acc = fmaf(n1, h1, acc);
            acc = fmaf(n2, h2, acc);
            acc = fmaf(n3, h3, acc);
        }
        for (; p < pe; ++p) {
            int e = eid[p];
            int s = srcA[e];
            acc = fmaf(dinv[s] * ew[e] * di, h[(size_t)s * HD + lane], acc);
        }
    }
    agg[(size_t)row * HD + lane] = acc;
}

// ---------------------------------------------------------------------------
// GEMMs + output (R5 structure, unchanged)
// ---------------------------------------------------------------------------
__global__ __launch_bounds__(256, 4) void k_gemm1(const float* __restrict__ x,
                                                  const float* __restrict__ W1,
                                                  float* __restrict__ h0) {
    __shared__ float sW[64 * HD];
    int tid = threadIdx.x;
    int rt  = tid >> 2;
    int cg  = (tid & 3) * 16;
    int base = blockIdx.x * 256;
    int rowc[4];
    bool rv[4];
#pragma unroll
    for (int r = 0; r < 4; ++r) {
        int row = base + rt + 64 * r;
        rv[r] = row < NN;
        rowc[r] = rv[r] ? row : (NN - 1);
    }
    float acc[4][16];
#pragma unroll
    for (int r = 0; r < 4; ++r)
#pragma unroll
        for (int c = 0; c < 16; ++c) acc[r][c] = 0.0f;

    for (int kc = 0; kc < IN_F; kc += 64) {
        __syncthreads();
        {
            const float4* wsrc = (const float4*)(W1 + (size_t)kc * HD);
            float4* wdst = (float4*)sW;
#pragma unroll
            for (int q = 0; q < 4; ++q) wdst[q * 256 + tid] = wsrc[q * 256 + tid];
        }
        __syncthreads();
        for (int k4 = 0; k4 < 16; ++k4) {
            float xs[4][4];
#pragma unroll
            for (int r = 0; r < 4; ++r)
                *(float4*)xs[r] = *(const float4*)(x + (size_t)rowc[r] * IN_F + kc + k4 * 4);
#pragma unroll
            for (int j = 0; j < 4; ++j) {
                float wv[16];
                const float4* wr4 = (const float4*)(sW + (k4 * 4 + j) * HD + cg);
#pragma unroll
                for (int q = 0; q < 4; ++q) ((float4*)wv)[q] = wr4[q];
#pragma unroll
                for (int r = 0; r < 4; ++r) {
                    float xj = xs[r][j];
#pragma unroll
                    for (int c = 0; c < 16; ++c) acc[r][c] = fmaf(xj, wv[c], acc[r][c]);
                }
            }
        }
    }
#pragma unroll
    for (int r = 0; r < 4; ++r) {
        if (!rv[r]) continue;
        float4* hp = (float4*)(h0 + (size_t)rowc[r] * HD + cg);
#pragma unroll
        for (int q = 0; q < 4; ++q)
            hp[q] = make_float4(acc[r][q * 4], acc[r][q * 4 + 1],
                                acc[r][q * 4 + 2], acc[r][q * 4 + 3]);
    }
}

template <bool BIASRELU>
__global__ __launch_bounds__(256, 4) void k_gemm64(const float* __restrict__ in,
                                                   const float* __restrict__ bin,
                                                   const float* __restrict__ W,
                                                   const float* __restrict__ bout,
                                                   float* __restrict__ outA) {
    __shared__ float sW[HD * HD];
    __shared__ float sBin[HD];
    int tid = threadIdx.x;
    int rt  = tid >> 2;
    int cg  = (tid & 3) * 16;
    int base = blockIdx.x * 256;
    int rowc[4];
    bool rv[4];
#pragma unroll
    for (int r = 0; r < 4; ++r) {
        int row = base + rt + 64 * r;
        rv[r] = row < NN;
        rowc[r] = rv[r] ? row : (NN - 1);
    }
    {
        const float4* wsrc = (const float4*)W;
        float4* wdst = (float4*)sW;
#pragma unroll
        for (int q = 0; q < 4; ++q) wdst[q * 256 + tid] = wsrc[q * 256 + tid];
        if (tid < 16) ((float4*)sBin)[tid] = ((const float4*)bin)[tid];
    }
    __syncthreads();
    float acc[4][16];
#pragma unroll
    for (int r = 0; r < 4; ++r)
#pragma unroll
        for (int c = 0; c < 16; ++c) acc[r][c] = 0.0f;

    for (int k4 = 0; k4 < 16; ++k4) {
        float bs[4];
        *(float4*)bs = ((const float4*)sBin)[k4];
        float xs[4][4];
#pragma unroll
        for (int r = 0; r < 4; ++r)
            *(float4*)xs[r] = *(const float4*)(in + (size_t)rowc[r] * HD + k4 * 4);
#pragma unroll
        for (int j = 0; j < 4; ++j) {
            float wv[16];
            const float4* wr4 = (const float4*)(sW + (k4 * 4 + j) * HD + cg);
#pragma unroll
            for (int q = 0; q < 4; ++q) ((float4*)wv)[q] = wr4[q];
#pragma unroll
            for (int r = 0; r < 4; ++r) {
                float hv = fmaxf(xs[r][j] + bs[j], 0.0f);
#pragma unroll
                for (int c = 0; c < 16; ++c) acc[r][c] = fmaf(hv, wv[c], acc[r][c]);
            }
        }
    }
#pragma unroll
    for (int r = 0; r < 4; ++r) {
        if (!rv[r]) continue;
        float4* ha = (float4*)(outA + (size_t)rowc[r] * HD + cg);
        if (BIASRELU) {
            float bo[16];
#pragma unroll
            for (int q = 0; q < 4; ++q) ((float4*)bo)[q] = *(const float4*)(bout + cg + q * 4);
#pragma unroll
            for (int q = 0; q < 4; ++q) {
                float4 v;
                v.x = fmaxf(acc[r][q * 4 + 0] + bo[q * 4 + 0], 0.0f);
                v.y = fmaxf(acc[r][q * 4 + 1] + bo[q * 4 + 1], 0.0f);
                v.z = fmaxf(acc[r][q * 4 + 2] + bo[q * 4 + 2], 0.0f);
                v.w = fmaxf(acc[r][q * 4 + 3] + bo[q * 4 + 3], 0.0f);
                ha[q] = v;
            }
        } else {
#pragma unroll
            for (int q = 0; q < 4; ++q)
                ha[q] = make_float4(acc[r][q * 4], acc[r][q * 4 + 1],
                                    acc[r][q * 4 + 2], acc[r][q * 4 + 3]);
        }
    }
}

// --- fallback path kernels ---
__global__ __launch_bounds__(256) void k_init_fb(float* __restrict__ deg) {
    int i = blockIdx.x * 256 + threadIdx.x;
    if (i < NN) deg[i] = 1.0f;
}
__global__ __launch_bounds__(256) void k_edge_fb(const int* __restrict__ dst,
                                                 const float* __restrict__ ew,
                                                 float* __restrict__ deg) {
    int e = blockIdx.x * 256 + threadIdx.x;
    if (e < NE) atomicAdd(&deg[dst[e]], ew[e]);
}
__global__ __launch_bounds__(256) void k_dinv_fb(float* __restrict__ deg) {
    int i = blockIdx.x * 256 + threadIdx.x;
    if (i < NN) {
        float d = deg[i];
        deg[i] = d > 0.0f ? rsqrtf(d) : 0.0f;
    }
}
__global__ __launch_bounds__(256) void k_selfloop(const float* __restrict__ h,
                                                  const float* __restrict__ dinv,
                                                  float* __restrict__ agg) {
    int i = blockIdx.x * 256 + threadIdx.x;
    if (i >= NN * (HD / 4)) return;
    int row = i / (HD / 4);
    float di = dinv[row];
    float d2 = di * di;
    float4 v = ((const float4*)h)[i];
    ((float4*)agg)[i] = make_float4(v.x * d2, v.y * d2, v.z * d2, v.w * d2);
}
__global__ __launch_bounds__(256) void k_scatter(const int* __restrict__ src,
                                                 const int* __restrict__ dst,
                                                 const float* __restrict__ ew,
                                                 const float* __restrict__ dinv,
                                                 const float* __restrict__ h,
                                                 float* __restrict__ agg) {
    int e = blockIdx.x * 4 + (threadIdx.x >> 6);
    int lane = threadIdx.x & 63;
    if (e >= NE) return;
    int s = src[e];
    int d = dst[e];
    float nrm = dinv[s] * ew[e] * dinv[d];
    float v = h[(size_t)s * HD + lane] * nrm;
    atomicAdd(&agg[(size_t)d * HD + lane], v);
}

// logits = h3 @ Wm2 + bm2, softmax. Wm2 (4 KB) in LDS, 4 rows/thread.
__global__ __launch_bounds__(256, 4) void k_out(const float* __restrict__ h3,
                                                const float* __restrict__ Wm2,
                                                const float* __restrict__ bm2,
                                                float* __restrict__ out) {
    __shared__ float sW[HD * NC];
    int tid = threadIdx.x;
    ((float4*)sW)[tid] = ((const float4*)Wm2)[tid];
    __syncthreads();
    int base = blockIdx.x * 1024;
    int rowc[4];
    bool rv[4];
#pragma unroll
    for (int r = 0; r < 4; ++r) {
        int row = base + tid * 4 + r;
        rv[r] = row < NN;
        rowc[r] = rv[r] ? row : (NN - 1);
    }
    float acc[4][16];
#pragma unroll
    for (int r = 0; r < 4; ++r)
#pragma unroll
        for (int c = 0; c < 16; ++c) acc[r][c] = 0.0f;

    for (int k4 = 0; k4 < 16; ++k4) {
        float xs[4][4];
#pragma unroll
        for (int r = 0; r < 4; ++r)
            *(float4*)xs[r] = *(const float4*)(h3 + (size_t)rowc[r] * HD + k4 * 4);
#pragma unroll
        for (int j = 0; j < 4; ++j) {
            float wv[16];
            const float4* wr4 = (const float4*)(sW + (k4 * 4 + j) * NC);
#pragma unroll
            for (int q = 0; q < 4; ++q) ((float4*)wv)[q] = wr4[q];
#pragma unroll
            for (int r = 0; r < 4; ++r) {
                float xj = xs[r][j];
#pragma unroll
                for (int c = 0; c < 16; ++c) acc[r][c] = fmaf(xj, wv[c], acc[r][c]);
            }
        }
    }
    float bm[16];
#pragma unroll
    for (int q = 0; q < 4; ++q) ((float4*)bm)[q] = ((const float4*)bm2)[q];
#pragma unroll
    for (int r = 0; r < 4; ++r) {
        if (!rv[r]) continue;
        float l[16];
#pragma unroll
        for (int c = 0; c < 16; ++c) l[c] = acc[r][c] + bm[c];
        float m = l[0];
#pragma unroll
        for (int c = 1; c < 16; ++c) m = fmaxf(m, l[c]);
        float ssum = 0.0f;
#pragma unroll
        for (int c = 0; c < 16; ++c) {
            l[c] = expf(l[c] - m);
            ssum += l[c];
        }
        float inv = 1.0f / ssum;
        float4* op = (float4*)(out + (size_t)rowc[r] * NC);
#pragma unroll
        for (int q = 0; q < 4; ++q)
            op[q] = make_float4(l[q * 4] * inv, l[q * 4 + 1] * inv,
                                l[q * 4 + 2] * inv, l[q * 4 + 3] * inv);
    }
}

extern "C" void kernel_launch(void* const* d_in, const int* in_sizes, int n_in,
                              void* d_out, int out_size, void* d_ws, size_t ws_size,
                              hipStream_t stream) {
    const float* x   = (const float*)d_in[0];
    const int*   ei  = (const int*)d_in[1];   // (2, E): [0,E)=src, [E,2E)=dst
    const float* ew  = (const float*)d_in[2];
    const float* W1  = (const float*)d_in[3];
    const float* b1  = (const float*)d_in[4];
    const float* W2  = (const float*)d_in[5];
    const float* b2  = (const float*)d_in[6];
    const float* Wm1 = (const float*)d_in[7];
    const float* bm1 = (const float*)d_in[8];
    const float* Wm2 = (const float*)d_in[9];
    const float* bm2 = (const float*)d_in[10];
    float* out = (float*)d_out;

    char* base = (char*)d_ws;
    float* dinv   = (float*)base;
    float* A      = (float*)(base + 400128);
    float* B      = (float*)(base + 26000128);
    int*   rowptr = (int*)(base + 51600128);        // (NN+1) ints
    int2*  pairsS = (int2*)(base + 52000256);       // FULL only
    // temporaries aliasing A / B before they're live:
    int2*  tmp    = (int2*)(base + 400128);         // in A, dead after k_sort
    int*   counts = (int*)(base + 26000128);        // in B, dead after agg1 ok
    int*   bsum   = (int*)(base + 26000128 + 306544);
    int*   bpref  = (int*)(base + 26000128 + 306944);

    const int* src = ei;
    const int* dst = ei + NE;

    const bool full  = ws_size >= (size_t)64800912;
    const bool douta = !full && ws_size >= (size_t)52000912;
    const int g_node = (NN + 255) / 256;   // 391
    const int g_gemm = (NN + 255) / 256;   // 391
    const int g_agg  = (NN + 3) / 4;       // 25000
    int* eid = (int*)d_out;

    if (full || douta) {
        // bucket build (LDS int atomics only)
        k_count<<<dim3(NBLK), dim3(256), 0, stream>>>(dst, counts);
        k_scan1<<<dim3(SCB), dim3(256), 0, stream>>>(counts, bsum);
        k_scan2<<<dim3(1), dim3(128), 0, stream>>>(bsum, bpref);
        k_scan3<<<dim3((CM + 255) / 256), dim3(256), 0, stream>>>(counts, bpref);
        if (full) {
            k_fill2<true><<<dim3(NBLK), dim3(256), 0, stream>>>(src, dst, ew, counts, tmp);
            k_sort<true><<<dim3(NT), dim3(256), 0, stream>>>(counts, tmp, pairsS, nullptr, rowptr);
            k_degdinv<true><<<dim3(g_node), dim3(256), 0, stream>>>(rowptr, pairsS, nullptr, ew, dinv);
        } else {
            k_fill2<false><<<dim3(NBLK), dim3(256), 0, stream>>>(src, dst, ew, counts, tmp);
            k_sort<false><<<dim3(NT), dim3(256), 0, stream>>>(counts, tmp, nullptr, eid, rowptr);
            k_degdinv<false><<<dim3(g_node), dim3(256), 0, stream>>>(rowptr, nullptr, eid, ew, dinv);
        }
        // gemm1 (clobbers tmp region of A — tmp is dead now)
        k_gemm1<<<dim3(g_gemm), dim3(256), 0, stream>>>(x, W1, A);
        // layer 1 aggregate (clobbers counts region of B — counts dead now)
        if (full)
            k_agg<true><<<dim3(g_agg), dim3(256), 0, stream>>>(rowptr, pairsS, nullptr, src, ew, dinv, A, B);
        else
            k_agg<false><<<dim3(g_agg), dim3(256), 0, stream>>>(rowptr, nullptr, eid, src, ew, dinv, A, B);
        // layer 2
        k_gemm64<false><<<dim3(g_gemm), dim3(256), 0, stream>>>(B, b1, W2, nullptr, A);
        if (full)
            k_agg<true><<<dim3(g_agg), dim3(256), 0, stream>>>(rowptr, pairsS, nullptr, src, ew, dinv, A, B);
        else
            k_agg<false><<<dim3(g_agg), dim3(256), 0, stream>>>(rowptr, nullptr, eid, src, ew, dinv, A, B);
        // MLP head + softmax
        k_gemm64<true><<<dim3(g_gemm), dim3(256), 0, stream>>>(B, b2, Wm1, bm1, A);
        k_out<<<dim3((NN + 1023) / 1024), dim3(256), 0, stream>>>(A, Wm2, bm2, out);
    } else {
        // fallback: atomic scatter
        k_init_fb<<<dim3(g_node), dim3(256), 0, stream>>>(dinv);
        k_edge_fb<<<dim3(NE / 256), dim3(256), 0, stream>>>(dst, ew, dinv);
        k_dinv_fb<<<dim3(g_node), dim3(256), 0, stream>>>(dinv);
        k_gemm1<<<dim3(g_gemm), dim3(256), 0, stream>>>(x, W1, A);
        k_selfloop<<<dim3((NN * (HD / 4) + 255) / 256), dim3(256), 0, stream>>>(A, dinv, B);
        k_scatter<<<dim3(NE / 4), dim3(256), 0, stream>>>(src, dst, ew, dinv, A, B);
        k_gemm64<false><<<dim3(g_gemm), dim3(256), 0, stream>>>(B, b1, W2, nullptr, A);
        k_selfloop<<<dim3((NN * (HD / 4) + 255) / 256), dim3(256), 0, stream>>>(A, dinv, B);
        k_scatter<<<dim3(NE / 4), dim3(256), 0, stream>>>(src, dst, ew, dinv, A, B);
        k_gemm64<true><<<dim3(g_gemm), dim3(256), 0, stream>>>(B, b2, Wm1, bm1, A);
        k_out<<<dim3((NN + 1023) / 1024), dim3(256), 0, stream>>>(A, Wm2, bm2, out);
    }
}

// Round 8
// 561.462 us; speedup vs baseline: 3.1939x; 1.0193x over previous
//
#include <hip/hip_runtime.h>
#include <cstdint>
#include <cstddef>

// Problem constants (match reference)
#define NN 100000   // nodes
#define NE 1600000  // edges
#define IN_F 256    // input feats
#define HD 64       // hidden width
#define NC 16       // classes

// Bucketed-build constants
#define NT 391      // dst tiles of 256 nodes: tile = dst >> 8
#define NBLK 196    // count/fill blocks
#define EPB 8192    // edges per count/fill block (NBLK*EPB >= NE)
#define CM (NT * NBLK)   // counts elems = 76,636
#define SCB 75      // scan blocks: ceil(CM/1024)

// ---------------------------------------------------------------------------
// Workspace layout (bytes) — guaranteed budget 52,000,912 (proven R4-R7):
//   dinv   @ 0             NN floats                              400,000
//   A      @ 400,128       NN*64 floats (h0 -> h2 -> h3)       25,600,000
//          (tmp int2[NE] = 12.8 MB aliases A BEFORE k_gemm1s runs)
//   B      @ 26,000,128    NN*64 floats (agg1 -> agg2)         25,600,000
//          (counts/bsum/bpref alias B's head, dead after k_sort;
//           gemm1s K-half-1 partial lives in B, dead after k_red)
//   rowptr @ 51,600,128    (NN+1) ints                             400,004
//   [FULL only] pairsS @ 52,000,256  NE int2 (src|dl<<17, ew)  12,800,000
// Configs (by ws_size, constant per run -> graph-safe):
//   FULL (ws >= 64,800,912): row-sorted (src,ew) pairs in ws; 1-indirection.
//   DOUT (ws >= 52,000,912): row-sorted edge-ids in d_out; 2-indirection.
//   FALLBACK (else): atomic-scatter path.
// No global atomics and no LDS *float* atomics anywhere on the main path.
// ---------------------------------------------------------------------------

// ---------------- tile-bucket build (LDS int atomics only) -----------------

__global__ __launch_bounds__(256) void k_count(const int* __restrict__ dstA,
                                               int* __restrict__ counts) {
    __shared__ int hist[NT];
    int tid = threadIdx.x;
    for (int t = tid; t < NT; t += 256) hist[t] = 0;
    __syncthreads();
    int base = blockIdx.x * EPB;
#pragma unroll
    for (int i = 0; i < 32; ++i) {
        int e = base + i * 256 + tid;
        if (e < NE) atomicAdd(&hist[dstA[e] >> 8], 1);  // native ds_add_u32
    }
    __syncthreads();
    for (int t = tid; t < NT; t += 256)
        counts[t * NBLK + blockIdx.x] = hist[t];
}

// exclusive scan of counts[CM] in place
__global__ __launch_bounds__(256) void k_scan1(int* __restrict__ c,
                                               int* __restrict__ bsum) {
    __shared__ int ss[256];
    int t = threadIdx.x;
    int base = blockIdx.x * 1024 + t * 4;
    int c0 = (base + 0 < CM) ? c[base + 0] : 0;
    int c1 = (base + 1 < CM) ? c[base + 1] : 0;
    int c2 = (base + 2 < CM) ? c[base + 2] : 0;
    int c3 = (base + 3 < CM) ? c[base + 3] : 0;
    int tsum = c0 + c1 + c2 + c3;
    ss[t] = tsum;
    __syncthreads();
    for (int off = 1; off < 256; off <<= 1) {
        int v = (t >= off) ? ss[t - off] : 0;
        __syncthreads();
        ss[t] += v;
        __syncthreads();
    }
    int excl = ss[t] - tsum;
    if (t == 255) bsum[blockIdx.x] = ss[255];
    if (base + 0 < CM) c[base + 0] = excl;
    if (base + 1 < CM) c[base + 1] = excl + c0;
    if (base + 2 < CM) c[base + 2] = excl + c0 + c1;
    if (base + 3 < CM) c[base + 3] = excl + c0 + c1 + c2;
}

__global__ __launch_bounds__(128) void k_scan2(const int* __restrict__ bsum,
                                               int* __restrict__ bpref) {
    __shared__ int ss[128];
    int t = threadIdx.x;
    int v = (t < SCB) ? bsum[t] : 0;
    ss[t] = v;
    __syncthreads();
    for (int off = 1; off < 128; off <<= 1) {
        int u = (t >= off) ? ss[t - off] : 0;
        __syncthreads();
        ss[t] += u;
        __syncthreads();
    }
    if (t < SCB) bpref[t] = ss[t] - v;
}

__global__ __launch_bounds__(256) void k_scan3(int* __restrict__ c,
                                               const int* __restrict__ bpref) {
    int i = blockIdx.x * 256 + threadIdx.x;
    if (i < CM) c[i] += bpref[i >> 10];
}

// fill tile buckets: tmp[pos] = FULL ? (src|dl<<17, ew) : (eid, dl)
template <bool FULL>
__global__ __launch_bounds__(256) void k_fill2(const int* __restrict__ srcA,
                                               const int* __restrict__ dstA,
                                               const float* __restrict__ ew,
                                               const int* __restrict__ counts,
                                               int2* __restrict__ tmp) {
    __shared__ int basel[NT];
    int tid = threadIdx.x;
    for (int t = tid; t < NT; t += 256) basel[t] = counts[t * NBLK + blockIdx.x];
    __syncthreads();
    int eb = blockIdx.x * EPB;
#pragma unroll
    for (int i = 0; i < 32; ++i) {
        int e = eb + i * 256 + tid;
        if (e < NE) {
            int d = dstA[e];
            int pos = atomicAdd(&basel[d >> 8], 1);  // native LDS int atomic
            if (FULL)
                tmp[pos] = make_int2(srcA[e] | ((d & 255) << 17),
                                     __float_as_int(ew[e]));
            else
                tmp[pos] = make_int2(e, d & 255);
        }
    }
}

// per-tile counting sort to row granularity. Writes rowptr + sorted payload.
template <bool FULL>
__global__ __launch_bounds__(256) void k_sort(const int* __restrict__ counts,
                                              const int2* __restrict__ tmp,
                                              int2* __restrict__ outP,
                                              int* __restrict__ outE,
                                              int* __restrict__ rowptr) {
    __shared__ int hist[256], ss[256], bases[256];
    int tid = threadIdx.x;
    int tile = blockIdx.x;
    int bs = counts[tile * NBLK];
    int be = (tile + 1 < NT) ? counts[(tile + 1) * NBLK] : NE;
    hist[tid] = 0;
    __syncthreads();
    for (int p = bs + tid; p < be; p += 256) {
        int dl = FULL ? ((tmp[p].x >> 17) & 255) : tmp[p].y;
        atomicAdd(&hist[dl], 1);  // native LDS int atomic
    }
    __syncthreads();
    int v = hist[tid];
    ss[tid] = v;
    __syncthreads();
    for (int off = 1; off < 256; off <<= 1) {
        int u = (tid >= off) ? ss[tid - off] : 0;
        __syncthreads();
        ss[tid] += u;
        __syncthreads();
    }
    int excl = ss[tid] - v;
    bases[tid] = bs + excl;
    int row = tile * 256 + tid;
    if (row < NN) rowptr[row] = bs + excl;
    if (tile == NT - 1 && tid == 0) rowptr[NN] = NE;
    __syncthreads();
    for (int p = bs + tid; p < be; p += 256) {
        int2 t2 = tmp[p];
        int dl = FULL ? ((t2.x >> 17) & 255) : t2.y;
        int pos = atomicAdd(&bases[dl], 1);
        if (FULL) outP[pos] = t2;
        else      outE[pos] = t2.x;
    }
}

// dinv[i] = rsqrt(1 + sum ew over row i)
template <bool FULL>
__global__ __launch_bounds__(256) void k_degdinv(const int* __restrict__ rowptr,
                                                 const int2* __restrict__ pairsS,
                                                 const int* __restrict__ eid,
                                                 const float* __restrict__ ew,
                                                 float* __restrict__ dinv) {
    int i = blockIdx.x * 256 + threadIdx.x;
    if (i >= NN) return;
    int p = rowptr[i], pe = rowptr[i + 1];
    float s = 1.0f;
    for (; p < pe; ++p)
        s += FULL ? __int_as_float(pairsS[p].y) : ew[eid[p]];
    dinv[i] = rsqrtf(s);
}

// aggregate: one wave per dst row, lane = feature, register accumulate.
template <bool FULL>
__global__ __launch_bounds__(256) void k_agg(const int* __restrict__ rowptr,
                                             const int2* __restrict__ pairsS,
                                             const int* __restrict__ eid,
                                             const int* __restrict__ srcA,
                                             const float* __restrict__ ew,
                                             const float* __restrict__ dinv,
                                             const float* __restrict__ h,
                                             float* __restrict__ agg) {
    int row = blockIdx.x * 4 + (threadIdx.x >> 6);
    int lane = threadIdx.x & 63;
    if (row >= NN) return;
    int p = rowptr[row], pe = rowptr[row + 1];
    float di = dinv[row];
    float acc = h[(size_t)row * HD + lane] * di * di;
    if (FULL) {
        for (; p + 4 <= pe; p += 4) {
            int2 v0 = pairsS[p], v1 = pairsS[p + 1],
                 v2 = pairsS[p + 2], v3 = pairsS[p + 3];
            int s0 = v0.x & 0x1FFFF, s1 = v1.x & 0x1FFFF,
                s2 = v2.x & 0x1FFFF, s3 = v3.x & 0x1FFFF;
            float h0 = h[(size_t)s0 * HD + lane];
            float h1 = h[(size_t)s1 * HD + lane];
            float h2 = h[(size_t)s2 * HD + lane];
            float h3 = h[(size_t)s3 * HD + lane];
            float n0 = dinv[s0] * __int_as_float(v0.y) * di;
            float n1 = dinv[s1] * __int_as_float(v1.y) * di;
            float n2 = dinv[s2] * __int_as_float(v2.y) * di;
            float n3 = dinv[s3] * __int_as_float(v3.y) * di;
            acc = fmaf(n0, h0, acc);
            acc = fmaf(n1, h1, acc);
            acc = fmaf(n2, h2, acc);
            acc = fmaf(n3, h3, acc);
        }
        for (; p < pe; ++p) {
            int2 v = pairsS[p];
            int s = v.x & 0x1FFFF;
            acc = fmaf(dinv[s] * __int_as_float(v.y) * di,
                       h[(size_t)s * HD + lane], acc);
        }
    } else {
        for (; p + 4 <= pe; p += 4) {
            int e0 = eid[p], e1 = eid[p + 1], e2 = eid[p + 2], e3 = eid[p + 3];
            int s0 = srcA[e0], s1 = srcA[e1], s2 = srcA[e2], s3 = srcA[e3];
            float h0 = h[(size_t)s0 * HD + lane];
            float h1 = h[(size_t)s1 * HD + lane];
            float h2 = h[(size_t)s2 * HD + lane];
            float h3 = h[(size_t)s3 * HD + lane];
            float n0 = dinv[s0] * ew[e0] * di;
            float n1 = dinv[s1] * ew[e1] * di;
            float n2 = dinv[s2] * ew[e2] * di;
            float n3 = dinv[s3] * ew[e3] * di;
            acc = fmaf(n0, h0, acc);
            acc = fmaf(n1, h1, acc);
            acc = fmaf(n2, h2, acc);
            acc = fmaf(n3, h3, acc);
        }
        for (; p < pe; ++p) {
            int e = eid[p];
            int s = srcA[e];
            acc = fmaf(dinv[s] * ew[e] * di, h[(size_t)s * HD + lane], acc);
        }
    }
    agg[(size_t)row * HD + lane] = acc;
}

// ---------------------------------------------------------------------------
// GEMM1 split-K: 782 blocks. Block b: rows tile (b>>1)*256, K-half (b&1)*128.
// Half 0 -> pA, half 1 -> pB. Same per-block LDS amortization as the 256-row
// tile, but 3 blocks/CU (12 waves/CU) to hide global x-load latency.
// ---------------------------------------------------------------------------
__global__ __launch_bounds__(256, 4) void k_gemm1s(const float* __restrict__ x,
                                                   const float* __restrict__ W1,
                                                   float* __restrict__ pA,
                                                   float* __restrict__ pB) {
    __shared__ float sW[64 * HD];
    int tid = threadIdx.x;
    int rt  = tid >> 2;
    int cg  = (tid & 3) * 16;
    int tile = blockIdx.x >> 1;
    int kb   = (blockIdx.x & 1) * 128;
    float* outp = (blockIdx.x & 1) ? pB : pA;
    int base = tile * 256;
    int rowc[4];
    bool rv[4];
#pragma unroll
    for (int r = 0; r < 4; ++r) {
        int row = base + rt + 64 * r;
        rv[r] = row < NN;
        rowc[r] = rv[r] ? row : (NN - 1);
    }
    float acc[4][16];
#pragma unroll
    for (int r = 0; r < 4; ++r)
#pragma unroll
        for (int c = 0; c < 16; ++c) acc[r][c] = 0.0f;

    for (int kc = kb; kc < kb + 128; kc += 64) {
        __syncthreads();
        {
            const float4* wsrc = (const float4*)(W1 + (size_t)kc * HD);
            float4* wdst = (float4*)sW;
#pragma unroll
            for (int q = 0; q < 4; ++q) wdst[q * 256 + tid] = wsrc[q * 256 + tid];
        }
        __syncthreads();
        for (int k4 = 0; k4 < 16; ++k4) {
            float xs[4][4];
#pragma unroll
            for (int r = 0; r < 4; ++r)
                *(float4*)xs[r] = *(const float4*)(x + (size_t)rowc[r] * IN_F + kc + k4 * 4);
#pragma unroll
            for (int j = 0; j < 4; ++j) {
                float wv[16];
                const float4* wr4 = (const float4*)(sW + (k4 * 4 + j) * HD + cg);
#pragma unroll
                for (int q = 0; q < 4; ++q) ((float4*)wv)[q] = wr4[q];
#pragma unroll
                for (int r = 0; r < 4; ++r) {
                    float xj = xs[r][j];
#pragma unroll
                    for (int c = 0; c < 16; ++c) acc[r][c] = fmaf(xj, wv[c], acc[r][c]);
                }
            }
        }
    }
#pragma unroll
    for (int r = 0; r < 4; ++r) {
        if (!rv[r]) continue;
        float4* hp = (float4*)(outp + (size_t)rowc[r] * HD + cg);
#pragma unroll
        for (int q = 0; q < 4; ++q)
            hp[q] = make_float4(acc[r][q * 4], acc[r][q * 4 + 1],
                                acc[r][q * 4 + 2], acc[r][q * 4 + 3]);
    }
}

// A += B (reduce the two K-halves). NN*HD floats.
__global__ __launch_bounds__(256) void k_red(float* __restrict__ A,
                                             const float* __restrict__ B) {
    int i = blockIdx.x * 256 + threadIdx.x;
    if (i >= NN * (HD / 4)) return;
    float4 a = ((const float4*)A)[i];
    float4 b = ((const float4*)B)[i];
    ((float4*)A)[i] = make_float4(a.x + b.x, a.y + b.y, a.z + b.z, a.w + b.w);
}

// ---------------------------------------------------------------------------
// gemm1 (fallback), gemm64, out
// ---------------------------------------------------------------------------
__global__ __launch_bounds__(256, 4) void k_gemm1(const float* __restrict__ x,
                                                  const float* __restrict__ W1,
                                                  float* __restrict__ h0) {
    __shared__ float sW[64 * HD];
    int tid = threadIdx.x;
    int rt  = tid >> 2;
    int cg  = (tid & 3) * 16;
    int base = blockIdx.x * 256;
    int rowc[4];
    bool rv[4];
#pragma unroll
    for (int r = 0; r < 4; ++r) {
        int row = base + rt + 64 * r;
        rv[r] = row < NN;
        rowc[r] = rv[r] ? row : (NN - 1);
    }
    float acc[4][16];
#pragma unroll
    for (int r = 0; r < 4; ++r)
#pragma unroll
        for (int c = 0; c < 16; ++c) acc[r][c] = 0.0f;

    for (int kc = 0; kc < IN_F; kc += 64) {
        __syncthreads();
        {
            const float4* wsrc = (const float4*)(W1 + (size_t)kc * HD);
            float4* wdst = (float4*)sW;
#pragma unroll
            for (int q = 0; q < 4; ++q) wdst[q * 256 + tid] = wsrc[q * 256 + tid];
        }
        __syncthreads();
        for (int k4 = 0; k4 < 16; ++k4) {
            float xs[4][4];
#pragma unroll
            for (int r = 0; r < 4; ++r)
                *(float4*)xs[r] = *(const float4*)(x + (size_t)rowc[r] * IN_F + kc + k4 * 4);
#pragma unroll
            for (int j = 0; j < 4; ++j) {
                float wv[16];
                const float4* wr4 = (const float4*)(sW + (k4 * 4 + j) * HD + cg);
#pragma unroll
                for (int q = 0; q < 4; ++q) ((float4*)wv)[q] = wr4[q];
#pragma unroll
                for (int r = 0; r < 4; ++r) {
                    float xj = xs[r][j];
#pragma unroll
                    for (int c = 0; c < 16; ++c) acc[r][c] = fmaf(xj, wv[c], acc[r][c]);
                }
            }
        }
    }
#pragma unroll
    for (int r = 0; r < 4; ++r) {
        if (!rv[r]) continue;
        float4* hp = (float4*)(h0 + (size_t)rowc[r] * HD + cg);
#pragma unroll
        for (int q = 0; q < 4; ++q)
            hp[q] = make_float4(acc[r][q * 4], acc[r][q * 4 + 1],
                                acc[r][q * 4 + 2], acc[r][q * 4 + 3]);
    }
}

template <bool BIASRELU>
__global__ __launch_bounds__(256, 4) void k_gemm64(const float* __restrict__ in,
                                                   const float* __restrict__ bin,
                                                   const float* __restrict__ W,
                                                   const float* __restrict__ bout,
                                                   float* __restrict__ outA) {
    __shared__ float sW[HD * HD];
    __shared__ float sBin[HD];
    int tid = threadIdx.x;
    int rt  = tid >> 2;
    int cg  = (tid & 3) * 16;
    int base = blockIdx.x * 256;
    int rowc[4];
    bool rv[4];
#pragma unroll
    for (int r = 0; r < 4; ++r) {
        int row = base + rt + 64 * r;
        rv[r] = row < NN;
        rowc[r] = rv[r] ? row : (NN - 1);
    }
    {
        const float4* wsrc = (const float4*)W;
        float4* wdst = (float4*)sW;
#pragma unroll
        for (int q = 0; q < 4; ++q) wdst[q * 256 + tid] = wsrc[q * 256 + tid];
        if (tid < 16) ((float4*)sBin)[tid] = ((const float4*)bin)[tid];
    }
    __syncthreads();
    float acc[4][16];
#pragma unroll
    for (int r = 0; r < 4; ++r)
#pragma unroll
        for (int c = 0; c < 16; ++c) acc[r][c] = 0.0f;

    for (int k4 = 0; k4 < 16; ++k4) {
        float bs[4];
        *(float4*)bs = ((const float4*)sBin)[k4];
        float xs[4][4];
#pragma unroll
        for (int r = 0; r < 4; ++r)
            *(float4*)xs[r] = *(const float4*)(in + (size_t)rowc[r] * HD + k4 * 4);
#pragma unroll
        for (int j = 0; j < 4; ++j) {
            float wv[16];
            const float4* wr4 = (const float4*)(sW + (k4 * 4 + j) * HD + cg);
#pragma unroll
            for (int q = 0; q < 4; ++q) ((float4*)wv)[q] = wr4[q];
#pragma unroll
            for (int r = 0; r < 4; ++r) {
                float hv = fmaxf(xs[r][j] + bs[j], 0.0f);
#pragma unroll
                for (int c = 0; c < 16; ++c) acc[r][c] = fmaf(hv, wv[c], acc[r][c]);
            }
        }
    }
#pragma unroll
    for (int r = 0; r < 4; ++r) {
        if (!rv[r]) continue;
        float4* ha = (float4*)(outA + (size_t)rowc[r] * HD + cg);
        if (BIASRELU) {
            float bo[16];
#pragma unroll
            for (int q = 0; q < 4; ++q) ((float4*)bo)[q] = *(const float4*)(bout + cg + q * 4);
#pragma unroll
            for (int q = 0; q < 4; ++q) {
                float4 v;
                v.x = fmaxf(acc[r][q * 4 + 0] + bo[q * 4 + 0], 0.0f);
                v.y = fmaxf(acc[r][q * 4 + 1] + bo[q * 4 + 1], 0.0f);
                v.z = fmaxf(acc[r][q * 4 + 2] + bo[q * 4 + 2], 0.0f);
                v.w = fmaxf(acc[r][q * 4 + 3] + bo[q * 4 + 3], 0.0f);
                ha[q] = v;
            }
        } else {
#pragma unroll
            for (int q = 0; q < 4; ++q)
                ha[q] = make_float4(acc[r][q * 4], acc[r][q * 4 + 1],
                                    acc[r][q * 4 + 2], acc[r][q * 4 + 3]);
        }
    }
}

// --- fallback path kernels ---
__global__ __launch_bounds__(256) void k_init_fb(float* __restrict__ deg) {
    int i = blockIdx.x * 256 + threadIdx.x;
    if (i < NN) deg[i] = 1.0f;
}
__global__ __launch_bounds__(256) void k_edge_fb(const int* __restrict__ dst,
                                                 const float* __restrict__ ew,
                                                 float* __restrict__ deg) {
    int e = blockIdx.x * 256 + threadIdx.x;
    if (e < NE) atomicAdd(&deg[dst[e]], ew[e]);
}
__global__ __launch_bounds__(256) void k_dinv_fb(float* __restrict__ deg) {
    int i = blockIdx.x * 256 + threadIdx.x;
    if (i < NN) {
        float d = deg[i];
        deg[i] = d > 0.0f ? rsqrtf(d) : 0.0f;
    }
}
__global__ __launch_bounds__(256) void k_selfloop(const float* __restrict__ h,
                                                  const float* __restrict__ dinv,
                                                  float* __restrict__ agg) {
    int i = blockIdx.x * 256 + threadIdx.x;
    if (i >= NN * (HD / 4)) return;
    int row = i / (HD / 4);
    float di = dinv[row];
    float d2 = di * di;
    float4 v = ((const float4*)h)[i];
    ((float4*)agg)[i] = make_float4(v.x * d2, v.y * d2, v.z * d2, v.w * d2);
}
__global__ __launch_bounds__(256) void k_scatter(const int* __restrict__ src,
                                                 const int* __restrict__ dst,
                                                 const float* __restrict__ ew,
                                                 const float* __restrict__ dinv,
                                                 const float* __restrict__ h,
                                                 float* __restrict__ agg) {
    int e = blockIdx.x * 4 + (threadIdx.x >> 6);
    int lane = threadIdx.x & 63;
    if (e >= NE) return;
    int s = src[e];
    int d = dst[e];
    float nrm = dinv[s] * ew[e] * dinv[d];
    float v = h[(size_t)s * HD + lane] * nrm;
    atomicAdd(&agg[(size_t)d * HD + lane], v);
}

// logits = h3 @ Wm2 + bm2, softmax. Wm2 (4 KB) in LDS, 4 rows/thread.
__global__ __launch_bounds__(256, 4) void k_out(const float* __restrict__ h3,
                                                const float* __restrict__ Wm2,
                                                const float* __restrict__ bm2,
                                                float* __restrict__ out) {
    __shared__ float sW[HD * NC];
    int tid = threadIdx.x;
    ((float4*)sW)[tid] = ((const float4*)Wm2)[tid];
    __syncthreads();
    int base = blockIdx.x * 1024;
    int rowc[4];
    bool rv[4];
#pragma unroll
    for (int r = 0; r < 4; ++r) {
        int row = base + tid * 4 + r;
        rv[r] = row < NN;
        rowc[r] = rv[r] ? row : (NN - 1);
    }
    float acc[4][16];
#pragma unroll
    for (int r = 0; r < 4; ++r)
#pragma unroll
        for (int c = 0; c < 16; ++c) acc[r][c] = 0.0f;

    for (int k4 = 0; k4 < 16; ++k4) {
        float xs[4][4];
#pragma unroll
        for (int r = 0; r < 4; ++r)
            *(float4*)xs[r] = *(const float4*)(h3 + (size_t)rowc[r] * HD + k4 * 4);
#pragma unroll
        for (int j = 0; j < 4; ++j) {
            float wv[16];
            const float4* wr4 = (const float4*)(sW + (k4 * 4 + j) * NC);
#pragma unroll
            for (int q = 0; q < 4; ++q) ((float4*)wv)[q] = wr4[q];
#pragma unroll
            for (int r = 0; r < 4; ++r) {
                float xj = xs[r][j];
#pragma unroll
                for (int c = 0; c < 16; ++c) acc[r][c] = fmaf(xj, wv[c], acc[r][c]);
            }
        }
    }
    float bm[16];
#pragma unroll
    for (int q = 0; q < 4; ++q) ((float4*)bm)[q] = ((const float4*)bm2)[q];
#pragma unroll
    for (int r = 0; r < 4; ++r) {
        if (!rv[r]) continue;
        float l[16];
#pragma unroll
        for (int c = 0; c < 16; ++c) l[c] = acc[r][c] + bm[c];
        float m = l[0];
#pragma unroll
        for (int c = 1; c < 16; ++c) m = fmaxf(m, l[c]);
        float ssum = 0.0f;
#pragma unroll
        for (int c = 0; c < 16; ++c) {
            l[c] = expf(l[c] - m);
            ssum += l[c];
        }
        float inv = 1.0f / ssum;
        float4* op = (float4*)(out + (size_t)rowc[r] * NC);
#pragma unroll
        for (int q = 0; q < 4; ++q)
            op[q] = make_float4(l[q * 4] * inv, l[q * 4 + 1] * inv,
                                l[q * 4 + 2] * inv, l[q * 4 + 3] * inv);
    }
}

extern "C" void kernel_launch(void* const* d_in, const int* in_sizes, int n_in,
                              void* d_out, int out_size, void* d_ws, size_t ws_size,
                              hipStream_t stream) {
    const float* x   = (const float*)d_in[0];
    const int*   ei  = (const int*)d_in[1];   // (2, E): [0,E)=src, [E,2E)=dst
    const float* ew  = (const float*)d_in[2];
    const float* W1  = (const float*)d_in[3];
    const float* b1  = (const float*)d_in[4];
    const float* W2  = (const float*)d_in[5];
    const float* b2  = (const float*)d_in[6];
    const float* Wm1 = (const float*)d_in[7];
    const float* bm1 = (const float*)d_in[8];
    const float* Wm2 = (const float*)d_in[9];
    const float* bm2 = (const float*)d_in[10];
    float* out = (float*)d_out;

    char* base = (char*)d_ws;
    float* dinv   = (float*)base;
    float* A      = (float*)(base + 400128);
    float* B      = (float*)(base + 26000128);
    int*   rowptr = (int*)(base + 51600128);        // (NN+1) ints
    int2*  pairsS = (int2*)(base + 52000256);       // FULL only
    // temporaries aliasing A / B before they're live:
    int2*  tmp    = (int2*)(base + 400128);         // in A, dead after k_sort
    int*   counts = (int*)(base + 26000128);        // in B, dead after k_sort
    int*   bsum   = (int*)(base + 26000128 + 306544);
    int*   bpref  = (int*)(base + 26000128 + 306944);

    const int* src = ei;
    const int* dst = ei + NE;

    const bool full  = ws_size >= (size_t)64800912;
    const bool douta = !full && ws_size >= (size_t)52000912;
    const int g_node = (NN + 255) / 256;   // 391
    const int g_gemm = (NN + 255) / 256;   // 391
    const int g_agg  = (NN + 3) / 4;       // 25000
    const int g_red  = (NN * (HD / 4) + 255) / 256;  // 6250
    int* eid = (int*)d_out;

    if (full || douta) {
        // bucket build (LDS int atomics only)
        k_count<<<dim3(NBLK), dim3(256), 0, stream>>>(dst, counts);
        k_scan1<<<dim3(SCB), dim3(256), 0, stream>>>(counts, bsum);
        k_scan2<<<dim3(1), dim3(128), 0, stream>>>(bsum, bpref);
        k_scan3<<<dim3((CM + 255) / 256), dim3(256), 0, stream>>>(counts, bpref);
        if (full) {
            k_fill2<true><<<dim3(NBLK), dim3(256), 0, stream>>>(src, dst, ew, counts, tmp);
            k_sort<true><<<dim3(NT), dim3(256), 0, stream>>>(counts, tmp, pairsS, nullptr, rowptr);
            k_degdinv<true><<<dim3(g_node), dim3(256), 0, stream>>>(rowptr, pairsS, nullptr, ew, dinv);
        } else {
            k_fill2<false><<<dim3(NBLK), dim3(256), 0, stream>>>(src, dst, ew, counts, tmp);
            k_sort<false><<<dim3(NT), dim3(256), 0, stream>>>(counts, tmp, nullptr, eid, rowptr);
            k_degdinv<false><<<dim3(g_node), dim3(256), 0, stream>>>(rowptr, nullptr, eid, ew, dinv);
        }
        // gemm1 split-K: halves into A and B (tmp/counts dead), then A += B
        k_gemm1s<<<dim3(NT * 2), dim3(256), 0, stream>>>(x, W1, A, B);
        k_red<<<dim3(g_red), dim3(256), 0, stream>>>(A, B);
        // layer 1 aggregate
        if (full)
            k_agg<true><<<dim3(g_agg), dim3(256), 0, stream>>>(rowptr, pairsS, nullptr, src, ew, dinv, A, B);
        else
            k_agg<false><<<dim3(g_agg), dim3(256), 0, stream>>>(rowptr, nullptr, eid, src, ew, dinv, A, B);
        // layer 2
        k_gemm64<false><<<dim3(g_gemm), dim3(256), 0, stream>>>(B, b1, W2, nullptr, A);
        if (full)
            k_agg<true><<<dim3(g_agg), dim3(256), 0, stream>>>(rowptr, pairsS, nullptr, src, ew, dinv, A, B);
        else
            k_agg<false><<<dim3(g_agg), dim3(256), 0, stream>>>(rowptr, nullptr, eid, src, ew, dinv, A, B);
        // MLP head + softmax
        k_gemm64<true><<<dim3(g_gemm), dim3(256), 0, stream>>>(B, b2, Wm1, bm1, A);
        k_out<<<dim3((NN + 1023) / 1024), dim3(256), 0, stream>>>(A, Wm2, bm2, out);
    } else {
        // fallback: atomic scatter
        k_init_fb<<<dim3(g_node), dim3(256), 0, stream>>>(dinv);
        k_edge_fb<<<dim3(NE / 256), dim3(256), 0, stream>>>(dst, ew, dinv);
        k_dinv_fb<<<dim3(g_node), dim3(256), 0, stream>>>(dinv);
        k_gemm1<<<dim3(g_gemm), dim3(256), 0, stream>>>(x, W1, A);
        k_selfloop<<<dim3(g_red), dim3(256), 0, stream>>>(A, dinv, B);
        k_scatter<<<dim3(NE / 4), dim3(256), 0, stream>>>(src, dst, ew, dinv, A, B);
        k_gemm64<false><<<dim3(g_gemm), dim3(256), 0, stream>>>(B, b1, W2, nullptr, A);
        k_selfloop<<<dim3(g_red), dim3(256), 0, stream>>>(A, dinv, B);
        k_scatter<<<dim3(NE / 4), dim3(256), 0, stream>>>(src, dst, ew, dinv, A, B);
        k_gemm64<true><<<dim3(g_gemm), dim3(256), 0, stream>>>(B, b2, Wm1, bm1, A);
        k_out<<<dim3((NN + 1023) / 1024), dim3(256), 0, stream>>>(A, Wm2, bm2, out);
    }
}